// Round 11
// baseline (269.899 us; speedup 1.0000x reference)
//
#include <hip/hip_runtime.h>
#include <hip/hip_bf16.h>
#include <hip/hip_fp16.h>
#include <stdint.h>

using bf16 = __hip_bfloat16;

typedef __bf16    bf16x8 __attribute__((ext_vector_type(8)));
typedef float     floatx4 __attribute__((ext_vector_type(4)));
typedef _Float16  f16x8 __attribute__((ext_vector_type(8)));

typedef __attribute__((address_space(3))) void as3_void;
typedef __attribute__((address_space(1))) void as1_void;

// async global->LDS, 16B/lane; LDS dest is wave-uniform base + lane*16.
#define GLD_LDS16(gp, lp) \
  __builtin_amdgcn_global_load_lds((as1_void*)(uintptr_t)(gp), (as3_void*)(uintptr_t)(lp), 16, 0, 0)

#define FENCE() asm volatile("" ::: "memory")
#define BAR()   do { FENCE(); __builtin_amdgcn_s_barrier(); FENCE(); } while (0)

// ---------------------------------------------------------------------------
// prep: blocks 0..1023 transpose W (fp32 [k][n] -> bf16 [n][k]); blocks
// 1024..3071 convert x fp32->bf16 (32 B stores/thread).
// ---------------------------------------------------------------------------
__global__ __launch_bounds__(256) void prep_kernel(
    const float* __restrict__ x,
    const float* __restrict__ Wq, const float* __restrict__ Wk,
    const float* __restrict__ Wv, const float* __restrict__ Wo,
    bf16* __restrict__ xbf, bf16* __restrict__ WTqkv, bf16* __restrict__ WoT) {
  __shared__ float tile[64 * 68];
  const int blk = blockIdx.x;
  const int tid = threadIdx.x;
  if (blk < 1024) {
    const int z = blk >> 8, t = blk & 255;
    const float* src = (z == 0) ? Wq : (z == 1) ? Wk : (z == 2) ? Wv : Wo;
    bf16* dst = (z < 3) ? (WTqkv + (size_t)z * 1024 * 1024) : WoT;
    const int nbase = (t & 15) * 64, kbase = (t >> 4) * 64;
    const int r1 = tid >> 4, c1 = tid & 15;
#pragma unroll
    for (int it = 0; it < 4; ++it) {
      const int row = r1 + it * 16;
      const float4 v = *(const float4*)(src + (size_t)(kbase + row) * 1024 + nbase + c1 * 4);
      *(float4*)(tile + row * 68 + c1 * 4) = v;
    }
    __syncthreads();
    const int c2 = tid & 7, n2 = tid >> 3;
#pragma unroll
    for (int it2 = 0; it2 < 2; ++it2) {
      const int n = n2 + it2 * 32;
      bf16 o[8];
#pragma unroll
      for (int s = 0; s < 8; ++s) o[s] = (bf16)tile[(8 * c2 + s) * 68 + n];
      *(uint4*)(dst + (size_t)(nbase + n) * 1024 + kbase + 8 * c2) = *(const uint4*)o;
    }
  } else {
    const size_t basei = ((size_t)(blk - 1024) * 256 + tid) * 16;
#pragma unroll
    for (int h = 0; h < 2; ++h) {
      const float4 a = *(const float4*)(x + basei + h * 8);
      const float4 b = *(const float4*)(x + basei + h * 8 + 4);
      bf16 o[8] = {(bf16)a.x, (bf16)a.y, (bf16)a.z, (bf16)a.w,
                   (bf16)b.x, (bf16)b.y, (bf16)b.z, (bf16)b.w};
      *(uint4*)(xbf + basei + h * 8) = *(const uint4*)o;
    }
  }
}

// ---------------------------------------------------------------------------
// QKV GEMM — BM=256 x BN=192, BK=64, grid 32x16 = 512 blocks = exact 2 rounds.
// R9: B taken OUT of LDS. B-frags (B[n=l16][k=quad*8+j], m120-verified, same
// pattern the attn kernel uses from global) are loaded straight from Bt into
// registers, double-buffered (bregA/bregB, static indexing), prefetched one
// K-tile ahead; L1/L2 serve the x4 cross-wave re-read. LDS holds only A
// (2x32KB dbuf): per-K-tile LDS traffic drops 160KB->64KB read + 32KB write,
// below the 1862-cyc MFMA floor. One barrier per K-tile (A-buffer WAR).
// Explicit vmcnt(12) at tile top retires the 4 A-stage loads (queue =
// 4 SAU + 12 B); compiler's own counted waits cover B-reg uses and leave
// the next A-stage in flight across the MFMA block.
// ---------------------------------------------------------------------------
#define SAU(bufi, u, kt) \
  GLD_LDS16(A + abase + (uint64_t)(u) * 65536 + (uint64_t)(kt) * 64, \
            (char*)Asp[bufi] + (u) * 8192 + ldst)

#define LDB12(bN, kt) do { \
    _Pragma("unroll") for (int _jb = 0; _jb < 6; ++_jb) { \
      bN[_jb][0] = *(const bf16x8*)(Bt + bof + (uint64_t)_jb * 16384 + (uint64_t)(kt) * 64); \
      bN[_jb][1] = *(const bf16x8*)(Bt + bof + (uint64_t)_jb * 16384 + (uint64_t)(kt) * 64 + 32); \
    } \
  } while (0)

#define KSTEP(curb, nxtb, bC, bN, ti, islast) do { \
    asm volatile("s_waitcnt vmcnt(12)" ::: "memory"); \
    BAR(); \
    if (!(islast)) { \
      SAU(nxtb, 0, (ti) + 1); SAU(nxtb, 1, (ti) + 1); \
      SAU(nxtb, 2, (ti) + 1); SAU(nxtb, 3, (ti) + 1); \
      LDB12(bN, (ti) + 1); \
    } \
    _Pragma("unroll") for (int _mb = 0; _mb < 4; ++_mb) { \
      const char* _p = (const char*)Asp[curb] + (wm * 64 + _mb * 16 + l16) * 128; \
      const bf16x8 _a0 = *(const bf16x8*)(_p + pcb0); \
      const bf16x8 _a1 = *(const bf16x8*)(_p + pcb1); \
      __builtin_amdgcn_s_setprio(1); \
      _Pragma("unroll") for (int _j = 0; _j < 6; ++_j) { \
        acc[_mb][_j] = __builtin_amdgcn_mfma_f32_16x16x32_bf16(_a0, bC[_j][0], acc[_mb][_j], 0, 0, 0); \
        acc[_mb][_j] = __builtin_amdgcn_mfma_f32_16x16x32_bf16(_a1, bC[_j][1], acc[_mb][_j], 0, 0, 0); \
      } \
      __builtin_amdgcn_s_setprio(0); \
    } \
  } while (0)

__global__ __launch_bounds__(512, 2) void gemm_qkv_8ph(
    const bf16* __restrict__ A, const bf16* __restrict__ Bt,
    const float* __restrict__ b0, const float* __restrict__ b1, const float* __restrict__ b2,
    __half* __restrict__ qkv) {
  const int t    = threadIdx.x;
  const int m0   = blockIdx.x * 256;
  const int n0   = blockIdx.y * 192;
  const int lane = t & 63;
  const int wave = t >> 6;      // 0..7
  const int wm   = wave >> 1;   // 0..3 -> 64-row strip
  const int wn   = wave & 1;    // 0..1 -> 96-col strip
  const int quad = lane >> 4;
  const int l16  = lane & 15;

  // A dbuf only: 2 x 32KB; epilogue reuses as 128-row restage (50KB).
  __shared__ alignas(16) char smem[65536];
  bf16* const Asp[2] = {(bf16*)smem, (bf16*)(smem + 32768)};

  // A staging: thread t -> linear LDS slot (row = srt, chunk = t&7);
  // global source pre-swizzled: chunk ^= row&7.
  const int srt = t >> 3;
  const int sct = ((t & 7) ^ (srt & 7)) << 3;
  const uint64_t abase = (uint64_t)(m0 + srt) * 1024 + sct;
  const int ldst = t * 16;

  // B frag base: lane l16 -> row n0+wn*96+l16, quad -> 16B k-offset.
  const uint64_t bof = (uint64_t)(n0 + wn * 96 + l16) * 1024 + quad * 8;

  const int pcb0 = ((quad) ^ (l16 & 7)) << 4;
  const int pcb1 = ((4 + quad) ^ (l16 & 7)) << 4;

  floatx4 acc[4][6];
#pragma unroll
  for (int i = 0; i < 4; ++i)
#pragma unroll
    for (int j = 0; j < 6; ++j) {
      floatx4 z = {0.f, 0.f, 0.f, 0.f};
      acc[i][j] = z;
    }
  bf16x8 bregA[6][2], bregB[6][2];

  // prologue: stage A tile0 -> buf0 (4 loads), load B tile0 -> bregA (12).
  SAU(0, 0, 0); SAU(0, 1, 0); SAU(0, 2, 0); SAU(0, 3, 0);
  LDB12(bregA, 0);

  // K loop: 16 tiles, 2 per unrolled iteration (named breg buffers).
#pragma unroll 1
  for (int ii = 0; ii < 8; ++ii) {
    KSTEP(0, 1, bregA, bregB, 2 * ii, false);
    KSTEP(1, 0, bregB, bregA, 2 * ii + 1, (ii == 7));
  }

  // epilogue: bias + f16; restage 128 rows per pass (50KB in 64KB LDS),
  // then coalesced f16x8 stores (6 per thread per pass).
  float bvs[6];
#pragma unroll
  for (int nj = 0; nj < 6; ++nj) {
    const int n = n0 + wn * 96 + nj * 16 + l16;
    const int which = n >> 10;
    const int c = n & 1023;
    bvs[nj] = ((which == 0) ? b0 : (which == 1) ? b1 : b2)[c];
  }
  _Float16* stg = (_Float16*)smem;
#pragma unroll
  for (int p = 0; p < 2; ++p) {
    BAR();
    if ((wm >> 1) == p) {
      const int lr0 = (wm & 1) * 64;
#pragma unroll
      for (int mb = 0; mb < 4; ++mb)
#pragma unroll
        for (int nj = 0; nj < 6; ++nj)
#pragma unroll
          for (int r = 0; r < 4; ++r)
            stg[(lr0 + mb * 16 + quad * 4 + r) * 200 + wn * 96 + nj * 16 + l16] =
                (_Float16)(acc[mb][nj][r] + bvs[nj]);
    }
    BAR();
#pragma unroll
    for (int rep = 0; rep < 6; ++rep) {
      const int cc = t + rep * 512;   // 0..3071 = 128 rows x 24 chunks
      const int rl = cc / 24;
      const int ch = cc - rl * 24;
      const f16x8 v = *(const f16x8*)(stg + rl * 200 + ch * 8);
      *(f16x8*)((_Float16*)qkv + (size_t)(m0 + p * 128 + rl) * 3072 + n0 + ch * 8) = v;
    }
  }
}

// ---------------------------------------------------------------------------
// Projection GEMM — 128x128 m97 structure. A row-major (8192,1024) bf16
// (attn output); Bt = Wo^T; out fp32 + bias.
// ---------------------------------------------------------------------------
__global__ __launch_bounds__(256) void gemm_proj(
    const bf16* __restrict__ A, const bf16* __restrict__ Bt,
    const float* __restrict__ bias, float* __restrict__ fout) {
  const int tid  = threadIdx.x;
  const int m0   = blockIdx.x * 128;
  const int n0   = blockIdx.y * 128;
  const int lane = tid & 63;
  const int wave = tid >> 6;
  const int wr   = (wave >> 1) * 64;
  const int wc   = (wave & 1) * 64;
  const int quad = lane >> 4;
  const int l16  = lane & 15;

  __shared__ alignas(16) bf16 As[128 * 64];
  __shared__ alignas(16) bf16 Bs[128 * 64];

  const int srow = tid >> 3;
  const int cg   = (tid & 7) ^ (srow & 7);
  const uint64_t aoff = (uint64_t)(m0 + srow) * 1024 + cg * 8;
  const uint64_t boff = (uint64_t)(n0 + srow) * 1024 + cg * 8;

  floatx4 acc[4][4];
#pragma unroll
  for (int i = 0; i < 4; ++i)
#pragma unroll
    for (int j = 0; j < 4; ++j) {
      floatx4 z = {0.f, 0.f, 0.f, 0.f};
      acc[i][j] = z;
    }

  for (int k0 = 0; k0 < 1024; k0 += 64) {
    __syncthreads();
#pragma unroll
    for (int it = 0; it < 4; ++it) {
      GLD_LDS16(A + aoff + (uint64_t)it * 32768 + k0, (char*)As + it * 4096 + tid * 16);
      GLD_LDS16(Bt + boff + (uint64_t)it * 32768 + k0, (char*)Bs + it * 4096 + tid * 16);
    }
    __syncthreads();

#pragma unroll
    for (int kc = 0; kc < 2; ++kc) {
      bf16x8 af[4], bfr[4];
#pragma unroll
      for (int i = 0; i < 4; ++i) {
        const int mrow = wr + i * 16 + l16;
        const int pca  = (kc * 4 + quad) ^ (mrow & 7);
        af[i] = *(const bf16x8*)(As + mrow * 64 + pca * 8);
        const int nrow = wc + i * 16 + l16;
        const int pcb  = (kc * 4 + quad) ^ (nrow & 7);
        bfr[i] = *(const bf16x8*)(Bs + nrow * 64 + pcb * 8);
      }
#pragma unroll
      for (int i = 0; i < 4; ++i)
#pragma unroll
        for (int j = 0; j < 4; ++j)
          acc[i][j] = __builtin_amdgcn_mfma_f32_16x16x32_bf16(af[i], bfr[j], acc[i][j], 0, 0, 0);
    }
  }

#pragma unroll
  for (int i = 0; i < 4; ++i)
#pragma unroll
    for (int j = 0; j < 4; ++j)
#pragma unroll
      for (int r = 0; r < 4; ++r) {
        const int m = m0 + wr + i * 16 + quad * 4 + r;
        const int n = n0 + wc + j * 16 + l16;
        fout[(uint64_t)m * 1024 + n] = acc[i][j][r] + bias[n];
      }
}

// ---------------------------------------------------------------------------
// Dilated attention — MFMA. Reads Q/K/V from row-major qkv (B,N,3072) f16;
// writes attn output row-major (B,N,1024) bf16.
// ---------------------------------------------------------------------------
#define RMAXA 32
#define VTS 176       // VT col stride (halves)
#define PS  104       // P row stride (halves)

__global__ __launch_bounds__(256) void dilated_attn_mfma_kernel(
    const __half* __restrict__ qkv, bf16* __restrict__ attn_out,
    const int* __restrict__ kptr, const int* __restrict__ dptr) {
  const int tid  = threadIdx.x;
  const int wave = tid >> 6, lane = tid & 63;
  const int quad = lane >> 4, l16 = lane & 15;
  const int bh = blockIdx.x >> 5;       // 32 query-blocks of 64 per (b,h)
  const int Q0 = (blockIdx.x & 31) * 64;
  const int b  = bh >> 4, h = bh & 15;
  const int kk  = kptr[0];
  const int dil = dptr[0];
  const int R   = kk * dil;
  const size_t xb = (size_t)b * 2048;
  const int qo = h * 64, ko = 1024 + h * 64, vo = 2048 + h * 64;
  const _Float16* Xh = (const _Float16*)qkv;

  __shared__ alignas(16) _Float16 smem[64 * VTS + 4 * 16 * PS];  // 35840 B
  _Float16* VT = smem;
  _Float16* Pw = smem + 64 * VTS + wave * 16 * PS;

  const bool fast = (R <= RMAXA) && (dil >= 1);

  if (fast) {
    // zero-fill VT + P (guards / pad cols must be 0, not stale/NaN bits)
    {
      const int nch = (64 * VTS + 4 * 16 * PS) / 8;
      const f16x8 z = {0, 0, 0, 0, 0, 0, 0, 0};
      for (int c = tid; c < nch; c += 256) ((f16x8*)smem)[c] = z;
    }
    __syncthreads();

    // stage V transposed: VT[dh][col], col = j - (Q0-R) + 32
    const int jlo = Q0 - R;  // unclamped
    const int lo = (jlo > 0) ? jlo : 0;
    const int hi = (Q0 + 63 + R < 2047) ? Q0 + 63 + R : 2047;
    const int nrows = hi - lo + 1;
    for (int idx = tid; idx < nrows * 8; idx += 256) {
      const int r = idx >> 3, c = idx & 7;
      const int j = lo + r;
      const f16x8 v = *(const f16x8*)(Xh + (xb + j) * 3072 + vo + c * 8);
      const int col = j - jlo + 32;
#pragma unroll
      for (int s = 0; s < 8; ++s) VT[(c * 8 + s) * VTS + col] = v[s];
    }
    __syncthreads();

    const int i0 = Q0 + wave * 16;
    // Q A-frags (2 k-chunks of 32 over DH=64)
    const f16x8 a0 = *(const f16x8*)(Xh + (xb + i0 + l16) * 3072 + qo + quad * 8);
    const f16x8 a1 = *(const f16x8*)(Xh + (xb + i0 + l16) * 3072 + qo + 32 + quad * 8);

    const int nkt = (16 + 2 * R + 15) >> 4;   // key tiles of 16
    const int jw0 = i0 - R;                   // wave key-window start
    float lsum[4] = {0.f, 0.f, 0.f, 0.f};
    const floatx4 zf = {0.f, 0.f, 0.f, 0.f};

    for (int kt = 0; kt < nkt; ++kt) {
      const int j0 = jw0 + 16 * kt;
      const int jn = j0 + l16;                        // this lane's key
      const int jc = (jn < 0) ? 0 : (jn > 2047 ? 2047 : jn);
      const f16x8 k0v = *(const f16x8*)(Xh + (xb + jc) * 3072 + ko + quad * 8);
      const f16x8 k1v = *(const f16x8*)(Xh + (xb + jc) * 3072 + ko + 32 + quad * 8);
      floatx4 s4 = __builtin_amdgcn_mfma_f32_16x16x32_f16(a0, k0v, zf, 0, 0, 0);
      s4 = __builtin_amdgcn_mfma_f32_16x16x32_f16(a1, k1v, s4, 0, 0, 0);
#pragma unroll
      for (int r = 0; r < 4; ++r) {
        const int m = quad * 4 + r;
        const int d = jn - (i0 + m);
        const bool valid = ((unsigned)jn < 2048u) && (d >= -R) && (d <= R) && (d % dil == 0);
        const float pe = valid ? __expf(s4[r] * 0.125f) : 0.f;
        lsum[r] += pe;
        Pw[m * PS + kt * 16 + l16] = (_Float16)pe;
      }
    }
    // row sums: reduce across the 16 lanes of each quad
#pragma unroll
    for (int r = 0; r < 4; ++r) {
      lsum[r] += __shfl_xor(lsum[r], 1);
      lsum[r] += __shfl_xor(lsum[r], 2);
      lsum[r] += __shfl_xor(lsum[r], 4);
      lsum[r] += __shfl_xor(lsum[r], 8);
    }

    // PV: o[t](16 x 16dh) accumulated f32; A = P[m=lane&15][k], B = VT
    const int nkc = (nkt * 16 + 31) >> 5;     // 32-wide k-chunks
    floatx4 o[4] = {zf, zf, zf, zf};
    const int vbase = 16 * wave + 32;         // VT col of k_rel = 0
    for (int c = 0; c < nkc; ++c) {
      const f16x8 pa = *(const f16x8*)(Pw + l16 * PS + c * 32 + quad * 8);
#pragma unroll
      for (int t = 0; t < 4; ++t) {
        const f16x8 vb = *(const f16x8*)(VT + (t * 16 + l16) * VTS + vbase + c * 32 + quad * 8);
        o[t] = __builtin_amdgcn_mfma_f32_16x16x32_f16(pa, vb, o[t], 0, 0, 0);
      }
    }

    // normalize + stage O into Pw ([m][dh], stride PS), then coalesced store
#pragma unroll
    for (int t = 0; t < 4; ++t) {
#pragma unroll
      for (int r = 0; r < 4; ++r)
        Pw[(quad * 4 + r) * PS + t * 16 + l16] = (_Float16)(o[t][r] / lsum[r]);
    }
    const int orow = lane >> 2, oseg = lane & 3;
#pragma unroll
    for (int hseg = 0; hseg < 2; ++hseg) {
      const f16x8 ov = *(const f16x8*)(Pw + orow * PS + oseg * 16 + hseg * 8);
      bf16 ob[8];
#pragma unroll
      for (int s = 0; s < 8; ++s) ob[s] = (bf16)(float)ov[s];
      *(uint4*)(attn_out + (xb + i0 + orow) * 1024 + h * 64 + oseg * 16 + hseg * 8) =
          *(const uint4*)ob;
    }
    return;
  }

  // ---- fallback: rarely taken; plain per-lane scalar loop ----
  if (tid < 64) {
    const int i = Q0 + tid;
    float l = 0.f;
    float oacc[64];
#pragma unroll
    for (int u = 0; u < 64; ++u) oacc[u] = 0.f;
    float qv[64];
#pragma unroll
    for (int u = 0; u < 64; ++u) qv[u] = (float)Xh[(xb + i) * 3072 + qo + u];
    for (int tt = -kk; tt <= kk; ++tt) {
      const int j = i + (int)((long long)tt * dil);
      if (j < 0 || j >= 2048) continue;
      float s = 0.f;
      for (int u = 0; u < 64; ++u) s += qv[u] * (float)Xh[(xb + j) * 3072 + ko + u];
      const float pe = __expf(s * 0.125f);
      l += pe;
      for (int u = 0; u < 64; ++u) oacc[u] += pe * (float)Xh[(xb + j) * 3072 + vo + u];
    }
    for (int u = 0; u < 64; ++u)
      attn_out[(xb + i) * 1024 + h * 64 + u] = (bf16)(oacc[u] / l);
  }
}

// ---------------------------------------------------------------------------
extern "C" void kernel_launch(void* const* d_in, const int* in_sizes, int n_in,
                              void* d_out, int out_size, void* d_ws, size_t ws_size,
                              hipStream_t stream) {
  const float* x  = (const float*)d_in[0];
  const float* Wq = (const float*)d_in[1];
  const float* bq = (const float*)d_in[2];
  const float* Wk = (const float*)d_in[3];
  const float* bk = (const float*)d_in[4];
  const float* Wv = (const float*)d_in[5];
  const float* bv = (const float*)d_in[6];
  const float* Wo = (const float*)d_in[7];
  const float* bo = (const float*)d_in[8];
  const int* kp   = (const int*)d_in[9];
  const int* dp   = (const int*)d_in[10];
  float* out = (float*)d_out;

  bf16*   xbf   = (bf16*)d_ws;                   // 8388608  (B,N,D) bf16
  bf16*   WTqkv = xbf + 8388608;                 // 3072*1024 bf16
  bf16*   WoT   = WTqkv + 3072 * 1024;           // 1024*1024 bf16
  __half* qkv   = (__half*)(WoT + 1024 * 1024);  // 8192*3072 f16 row-major
  bf16*   attnO = xbf;                           // alias: (B,N,1024) bf16

  prep_kernel<<<dim3(3072), 256, 0, stream>>>(x, Wq, Wk, Wv, Wo, xbf, WTqkv, WoT);

  gemm_qkv_8ph<<<dim3(32, 16), 512, 0, stream>>>(xbf, WTqkv, bq, bk, bv, qkv);

  dilated_attn_mfma_kernel<<<dim3(2048), 256, 0, stream>>>(qkv, attnO, kp, dp);

  gemm_proj<<<dim3(64, 8), 256, 0, stream>>>(attnO, WoT, bo, out);
}

// Round 12
// 214.254 us; speedup vs baseline: 1.2597x; 1.2597x over previous
//
#include <hip/hip_runtime.h>
#include <hip/hip_bf16.h>
#include <hip/hip_fp16.h>
#include <stdint.h>

using bf16 = __hip_bfloat16;

typedef __bf16    bf16x8 __attribute__((ext_vector_type(8)));
typedef float     floatx4 __attribute__((ext_vector_type(4)));
typedef _Float16  f16x8 __attribute__((ext_vector_type(8)));

typedef __attribute__((address_space(3))) void as3_void;
typedef __attribute__((address_space(1))) void as1_void;

// async global->LDS, 16B/lane; LDS dest is wave-uniform base + lane*16.
#define GLD_LDS16(gp, lp) \
  __builtin_amdgcn_global_load_lds((as1_void*)(uintptr_t)(gp), (as3_void*)(uintptr_t)(lp), 16, 0, 0)

#define FENCE() asm volatile("" ::: "memory")
#define BAR()   do { FENCE(); __builtin_amdgcn_s_barrier(); FENCE(); } while (0)
// pin everything (MFMAs + their compiler-inserted lgkm waits) before the
// following barrier; no lgkmcnt(0) — compiler interleaves fine-grained waits.
#define PIN()   __builtin_amdgcn_sched_barrier(0)

// ---------------------------------------------------------------------------
// prep: blocks 0..1023 transpose W (fp32 [k][n] -> bf16 [n][k]); blocks
// 1024..3071 convert x fp32->bf16 (32 B stores/thread).
// ---------------------------------------------------------------------------
__global__ __launch_bounds__(256) void prep_kernel(
    const float* __restrict__ x,
    const float* __restrict__ Wq, const float* __restrict__ Wk,
    const float* __restrict__ Wv, const float* __restrict__ Wo,
    bf16* __restrict__ xbf, bf16* __restrict__ WTqkv, bf16* __restrict__ WoT) {
  __shared__ float tile[64 * 68];
  const int blk = blockIdx.x;
  const int tid = threadIdx.x;
  if (blk < 1024) {
    const int z = blk >> 8, t = blk & 255;
    const float* src = (z == 0) ? Wq : (z == 1) ? Wk : (z == 2) ? Wv : Wo;
    bf16* dst = (z < 3) ? (WTqkv + (size_t)z * 1024 * 1024) : WoT;
    const int nbase = (t & 15) * 64, kbase = (t >> 4) * 64;
    const int r1 = tid >> 4, c1 = tid & 15;
#pragma unroll
    for (int it = 0; it < 4; ++it) {
      const int row = r1 + it * 16;
      const float4 v = *(const float4*)(src + (size_t)(kbase + row) * 1024 + nbase + c1 * 4);
      *(float4*)(tile + row * 68 + c1 * 4) = v;
    }
    __syncthreads();
    const int c2 = tid & 7, n2 = tid >> 3;
#pragma unroll
    for (int it2 = 0; it2 < 2; ++it2) {
      const int n = n2 + it2 * 32;
      bf16 o[8];
#pragma unroll
      for (int s = 0; s < 8; ++s) o[s] = (bf16)tile[(8 * c2 + s) * 68 + n];
      *(uint4*)(dst + (size_t)(nbase + n) * 1024 + kbase + 8 * c2) = *(const uint4*)o;
    }
  } else {
    const size_t basei = ((size_t)(blk - 1024) * 256 + tid) * 16;
#pragma unroll
    for (int h = 0; h < 2; ++h) {
      const float4 a = *(const float4*)(x + basei + h * 8);
      const float4 b = *(const float4*)(x + basei + h * 8 + 4);
      bf16 o[8] = {(bf16)a.x, (bf16)a.y, (bf16)a.z, (bf16)a.w,
                   (bf16)b.x, (bf16)b.y, (bf16)b.z, (bf16)b.w};
      *(uint4*)(xbf + basei + h * 8) = *(const uint4*)o;
    }
  }
}

// ---------------------------------------------------------------------------
// QKV GEMM — R8 kernel verbatim (measured 54.9 us, 938 TF, MfmaUtil 39%).
// BM=256 x BN=192, BK=64, grid 32x16 = 512 blocks = exact 2 rounds.
// 2 phases/K-tile of 24 MFMA; stage slots never touch a region read in the
// same phase; drains vmcnt(3) at A2/B2 end; PIN pins MFMA+waits before BAR.
// R9's B-in-registers REVERTED: at VGPR=116 the compiler sank the B prefetch
// loads to their uses (96-VGPR dbuf not kept live), exposing raw latency
// per tile (125 us, MfmaUtil 16%). B stays in LDS.
// ---------------------------------------------------------------------------
#define SAU(bufi, u, kt) \
  GLD_LDS16(A + abase + (uint64_t)(u) * 65536 + (uint64_t)(kt) * 64, \
            (char*)Asp[bufi] + (u) * 8192 + ldst)
#define SBU(bufi, u, kt) \
  GLD_LDS16(Bt + bbase + (uint64_t)(u) * 65536 + (uint64_t)(kt) * 64, \
            (char*)Bsp[bufi] + (u) * 8192 + ldst)

#define RDA2(bufi, mb) do { \
    const char* _p = (const char*)Asp[bufi] + (wm * 64 + (mb) * 16 + l16) * 128; \
    af[0][0] = *(const bf16x8*)(_p + pcb0); \
    af[0][1] = *(const bf16x8*)(_p + pcb1); \
    af[1][0] = *(const bf16x8*)(_p + 2048 + pcb0); \
    af[1][1] = *(const bf16x8*)(_p + 2048 + pcb1); \
  } while (0)

#define RDB6(bufi) do { \
    const char* _p = (const char*)Bsp[bufi] + (wn * 96 + l16) * 128; \
    _Pragma("unroll") for (int _j = 0; _j < 6; ++_j) { \
      bfr[_j][0] = *(const bf16x8*)(_p + _j * 2048 + pcb0); \
      bfr[_j][1] = *(const bf16x8*)(_p + _j * 2048 + pcb1); \
    } \
  } while (0)

#define MMQ24(mb) do { \
    _Pragma("unroll") for (int _i = 0; _i < 2; ++_i) \
      _Pragma("unroll") for (int _j = 0; _j < 6; ++_j) \
        _Pragma("unroll") for (int _k = 0; _k < 2; ++_k) \
          acc[(mb) + _i][_j] = __builtin_amdgcn_mfma_f32_16x16x32_bf16( \
              af[_i][_k], bfr[_j][_k], acc[(mb) + _i][_j], 0, 0, 0); \
  } while (0)

__global__ __launch_bounds__(512, 2) void gemm_qkv_8ph(
    const bf16* __restrict__ A, const bf16* __restrict__ Bt,
    const float* __restrict__ b0, const float* __restrict__ b1, const float* __restrict__ b2,
    __half* __restrict__ qkv) {
  const int t    = threadIdx.x;
  const int m0   = blockIdx.x * 256;
  const int n0   = blockIdx.y * 192;
  const int lane = t & 63;
  const int wave = t >> 6;      // 0..7
  const int wm   = wave >> 1;   // 0..3 -> 64-row strip
  const int wn   = wave & 1;    // 0..1 -> 96-col strip
  const int quad = lane >> 4;
  const int l16  = lane & 15;

  // A dbuf 2x32KB @0, B dbuf 2x24KB @65536; epilogue reuses all 112KB.
  __shared__ alignas(16) char smem[114688];
  bf16* const Asp[2] = {(bf16*)smem, (bf16*)(smem + 32768)};
  bf16* const Bsp[2] = {(bf16*)(smem + 65536), (bf16*)(smem + 90112)};

  // staging: thread t -> linear LDS slot (row = srt within 64-row unit,
  // chunk = t&7); global source pre-swizzled: chunk ^= row&7.
  const int srt = t >> 3;
  const int sct = ((t & 7) ^ (srt & 7)) << 3;
  const uint64_t abase = (uint64_t)(m0 + srt) * 1024 + sct;
  const uint64_t bbase = (uint64_t)(n0 + srt) * 1024 + sct;
  const int ldst = t * 16;

  const int pcb0 = ((quad) ^ (l16 & 7)) << 4;
  const int pcb1 = ((4 + quad) ^ (l16 & 7)) << 4;

  floatx4 acc[4][6];
#pragma unroll
  for (int i = 0; i < 4; ++i)
#pragma unroll
    for (int j = 0; j < 6; ++j) {
      floatx4 z = {0.f, 0.f, 0.f, 0.f};
      acc[i][j] = z;
    }
  bf16x8 af[2][2], bfr[6][2];

  // prologue: t0 full (7 units) -> buf0; t1.B (3 units) -> buf1.
  SBU(0, 0, 0); SBU(0, 1, 0); SBU(0, 2, 0);
  SAU(0, 0, 0); SAU(0, 1, 0); SAU(0, 2, 0); SAU(0, 3, 0);
  SBU(1, 0, 1); SBU(1, 1, 1); SBU(1, 2, 1);
  asm volatile("s_waitcnt vmcnt(3)" ::: "memory");  // t0's 7 arrived
  BAR();

  for (int i = 0; i < 8; ++i) {
    const int kt1 = 2 * i + 1;
    const int kt2 = 2 * i + 2;
    const int kt3 = 2 * i + 3;
    const bool pf = (i < 7);

    // A1: read buf0 A[mb0-1]+B(all); stage buf1.A0-3 (t1; free since prev B2)
    RDA2(0, 0); RDB6(0);
    SAU(1, 0, kt1); SAU(1, 1, kt1); SAU(1, 2, kt1); SAU(1, 3, kt1);
    __builtin_amdgcn_s_setprio(1); MMQ24(0); __builtin_amdgcn_s_setprio(0);
    PIN();
    BAR();

    // A2: read buf0 A[mb2-3]; stage buf0.B0-2 (t2; free after A1); drain t1
    RDA2(0, 2);
    if (pf) { SBU(0, 0, kt2); SBU(0, 1, kt2); SBU(0, 2, kt2); }
    __builtin_amdgcn_s_setprio(1); MMQ24(2); __builtin_amdgcn_s_setprio(0);
    PIN();
    if (pf) { asm volatile("s_waitcnt vmcnt(3)" ::: "memory"); }
    else    { asm volatile("s_waitcnt vmcnt(0)" ::: "memory"); }
    BAR();

    // B1: read buf1 A[mb0-1]+B(all); stage buf0.A0-3 (t2; free after A2)
    RDA2(1, 0); RDB6(1);
    if (pf) { SAU(0, 0, kt2); SAU(0, 1, kt2); SAU(0, 2, kt2); SAU(0, 3, kt2); }
    __builtin_amdgcn_s_setprio(1); MMQ24(0); __builtin_amdgcn_s_setprio(0);
    PIN();
    BAR();

    // B2: read buf1 A[mb2-3]; stage buf1.B0-2 (t3; free after B1); drain t2
    RDA2(1, 2);
    if (pf) { SBU(1, 0, kt3); SBU(1, 1, kt3); SBU(1, 2, kt3); }
    __builtin_amdgcn_s_setprio(1); MMQ24(2); __builtin_amdgcn_s_setprio(0);
    PIN();
    if (pf) { asm volatile("s_waitcnt vmcnt(3)" ::: "memory"); }
    BAR();
  }

  // epilogue: bias + f16; single LDS restage (256 rows x stride 200 halves =
  // 100KB over smem), one barrier, then 12 coalesced f16x8 stores per thread.
  float bvs[6];
#pragma unroll
  for (int nj = 0; nj < 6; ++nj) {
    const int n = n0 + wn * 96 + nj * 16 + l16;
    const int which = n >> 10;
    const int c = n & 1023;
    bvs[nj] = ((which == 0) ? b0 : (which == 1) ? b1 : b2)[c];
  }
  _Float16* stg = (_Float16*)smem;
#pragma unroll
  for (int mb = 0; mb < 4; ++mb)
#pragma unroll
    for (int nj = 0; nj < 6; ++nj)
#pragma unroll
      for (int r = 0; r < 4; ++r)
        stg[(wm * 64 + mb * 16 + quad * 4 + r) * 200 + wn * 96 + nj * 16 + l16] =
            (_Float16)(acc[mb][nj][r] + bvs[nj]);
  BAR();
#pragma unroll
  for (int rep = 0; rep < 12; ++rep) {
    const int cc = t + rep * 512;     // 0..6143 = 256 rows x 24 chunks
    const int rl = cc / 24;
    const int ch = cc - rl * 24;
    const f16x8 v = *(const f16x8*)(stg + rl * 200 + ch * 8);
    *(f16x8*)((_Float16*)qkv + (size_t)(m0 + rl) * 3072 + n0 + ch * 8) = v;
  }
}

// ---------------------------------------------------------------------------
// Projection GEMM — 128x128 m97 structure. A row-major (8192,1024) bf16
// (attn output); Bt = Wo^T; out fp32 + bias.
// ---------------------------------------------------------------------------
__global__ __launch_bounds__(256) void gemm_proj(
    const bf16* __restrict__ A, const bf16* __restrict__ Bt,
    const float* __restrict__ bias, float* __restrict__ fout) {
  const int tid  = threadIdx.x;
  const int m0   = blockIdx.x * 128;
  const int n0   = blockIdx.y * 128;
  const int lane = tid & 63;
  const int wave = tid >> 6;
  const int wr   = (wave >> 1) * 64;
  const int wc   = (wave & 1) * 64;
  const int quad = lane >> 4;
  const int l16  = lane & 15;

  __shared__ alignas(16) bf16 As[128 * 64];
  __shared__ alignas(16) bf16 Bs[128 * 64];

  const int srow = tid >> 3;
  const int cg   = (tid & 7) ^ (srow & 7);
  const uint64_t aoff = (uint64_t)(m0 + srow) * 1024 + cg * 8;
  const uint64_t boff = (uint64_t)(n0 + srow) * 1024 + cg * 8;

  floatx4 acc[4][4];
#pragma unroll
  for (int i = 0; i < 4; ++i)
#pragma unroll
    for (int j = 0; j < 4; ++j) {
      floatx4 z = {0.f, 0.f, 0.f, 0.f};
      acc[i][j] = z;
    }

  for (int k0 = 0; k0 < 1024; k0 += 64) {
    __syncthreads();
#pragma unroll
    for (int it = 0; it < 4; ++it) {
      GLD_LDS16(A + aoff + (uint64_t)it * 32768 + k0, (char*)As + it * 4096 + tid * 16);
      GLD_LDS16(Bt + boff + (uint64_t)it * 32768 + k0, (char*)Bs + it * 4096 + tid * 16);
    }
    __syncthreads();

#pragma unroll
    for (int kc = 0; kc < 2; ++kc) {
      bf16x8 af[4], bfr[4];
#pragma unroll
      for (int i = 0; i < 4; ++i) {
        const int mrow = wr + i * 16 + l16;
        const int pca  = (kc * 4 + quad) ^ (mrow & 7);
        af[i] = *(const bf16x8*)(As + mrow * 64 + pca * 8);
        const int nrow = wc + i * 16 + l16;
        const int pcb  = (kc * 4 + quad) ^ (nrow & 7);
        bfr[i] = *(const bf16x8*)(Bs + nrow * 64 + pcb * 8);
      }
#pragma unroll
      for (int i = 0; i < 4; ++i)
#pragma unroll
        for (int j = 0; j < 4; ++j)
          acc[i][j] = __builtin_amdgcn_mfma_f32_16x16x32_bf16(af[i], bfr[j], acc[i][j], 0, 0, 0);
    }
  }

#pragma unroll
  for (int i = 0; i < 4; ++i)
#pragma unroll
    for (int j = 0; j < 4; ++j)
#pragma unroll
      for (int r = 0; r < 4; ++r) {
        const int m = m0 + wr + i * 16 + quad * 4 + r;
        const int n = n0 + wc + j * 16 + l16;
        fout[(uint64_t)m * 1024 + n] = acc[i][j][r] + bias[n];
      }
}

// ---------------------------------------------------------------------------
// Dilated attention — R12: 128 queries/block, 8 waves (1024 blocks x 512
// thr). Per-wave math identical to the 64-query version (wave owns 16
// queries, same nkt/vbase/P layout); VT window, zero-fill, and V-transpose
// staging amortize 2x better. VTS=240: wave7 max read col = 144+64+31 = 239
// (guard verified at R=RMAXA); written cols <= 191; LDS 57344 B -> 2
// blocks/CU, 16 waves/CU (same residency as before), 1024 blocks = 2 rounds.
// ---------------------------------------------------------------------------
#define RMAXA 32
#define VTS 240       // VT col stride (halves); max read col 239 at R=32
#define PS  104       // P row stride (halves)

__global__ __launch_bounds__(512) void dilated_attn_mfma_kernel(
    const __half* __restrict__ qkv, bf16* __restrict__ attn_out,
    const int* __restrict__ kptr, const int* __restrict__ dptr) {
  const int tid  = threadIdx.x;
  const int wave = tid >> 6, lane = tid & 63;
  const int quad = lane >> 4, l16 = lane & 15;
  const int bh = blockIdx.x >> 4;       // 16 query-blocks of 128 per (b,h)
  const int Q0 = (blockIdx.x & 15) * 128;
  const int b  = bh >> 4, h = bh & 15;
  const int kk  = kptr[0];
  const int dil = dptr[0];
  const int R   = kk * dil;
  const size_t xb = (size_t)b * 2048;
  const int qo = h * 64, ko = 1024 + h * 64, vo = 2048 + h * 64;
  const _Float16* Xh = (const _Float16*)qkv;

  __shared__ alignas(16) _Float16 smem[64 * VTS + 8 * 16 * PS];  // 57344 B
  _Float16* VT = smem;
  _Float16* Pw = smem + 64 * VTS + wave * 16 * PS;

  const bool fast = (R <= RMAXA) && (dil >= 1);

  if (fast) {
    // zero-fill VT + P (guards / pad cols must be 0, not stale/NaN bits)
    {
      const int nch = (64 * VTS + 8 * 16 * PS) / 8;   // 3584
      const f16x8 z = {0, 0, 0, 0, 0, 0, 0, 0};
      for (int c = tid; c < nch; c += 512) ((f16x8*)smem)[c] = z;
    }
    __syncthreads();

    // stage V transposed: VT[dh][col], col = j - (Q0-R) + 32
    const int jlo = Q0 - R;  // unclamped
    const int lo = (jlo > 0) ? jlo : 0;
    const int hi = (Q0 + 127 + R < 2047) ? Q0 + 127 + R : 2047;
    const int nrows = hi - lo + 1;
    for (int idx = tid; idx < nrows * 8; idx += 512) {
      const int r = idx >> 3, c = idx & 7;
      const int j = lo + r;
      const f16x8 v = *(const f16x8*)(Xh + (xb + j) * 3072 + vo + c * 8);
      const int col = j - jlo + 32;
#pragma unroll
      for (int s = 0; s < 8; ++s) VT[(c * 8 + s) * VTS + col] = v[s];
    }
    __syncthreads();

    const int i0 = Q0 + wave * 16;
    // Q A-frags (2 k-chunks of 32 over DH=64)
    const f16x8 a0 = *(const f16x8*)(Xh + (xb + i0 + l16) * 3072 + qo + quad * 8);
    const f16x8 a1 = *(const f16x8*)(Xh + (xb + i0 + l16) * 3072 + qo + 32 + quad * 8);

    const int nkt = (16 + 2 * R + 15) >> 4;   // key tiles of 16
    const int jw0 = i0 - R;                   // wave key-window start
    float lsum[4] = {0.f, 0.f, 0.f, 0.f};
    const floatx4 zf = {0.f, 0.f, 0.f, 0.f};

    for (int kt = 0; kt < nkt; ++kt) {
      const int j0 = jw0 + 16 * kt;
      const int jn = j0 + l16;                        // this lane's key
      const int jc = (jn < 0) ? 0 : (jn > 2047 ? 2047 : jn);
      const f16x8 k0v = *(const f16x8*)(Xh + (xb + jc) * 3072 + ko + quad * 8);
      const f16x8 k1v = *(const f16x8*)(Xh + (xb + jc) * 3072 + ko + 32 + quad * 8);
      floatx4 s4 = __builtin_amdgcn_mfma_f32_16x16x32_f16(a0, k0v, zf, 0, 0, 0);
      s4 = __builtin_amdgcn_mfma_f32_16x16x32_f16(a1, k1v, s4, 0, 0, 0);
#pragma unroll
      for (int r = 0; r < 4; ++r) {
        const int m = quad * 4 + r;
        const int d = jn - (i0 + m);
        const bool valid = ((unsigned)jn < 2048u) && (d >= -R) && (d <= R) && (d % dil == 0);
        const float pe = valid ? __expf(s4[r] * 0.125f) : 0.f;
        lsum[r] += pe;
        Pw[m * PS + kt * 16 + l16] = (_Float16)pe;
      }
    }
    // row sums: reduce across the 16 lanes of each quad
#pragma unroll
    for (int r = 0; r < 4; ++r) {
      lsum[r] += __shfl_xor(lsum[r], 1);
      lsum[r] += __shfl_xor(lsum[r], 2);
      lsum[r] += __shfl_xor(lsum[r], 4);
      lsum[r] += __shfl_xor(lsum[r], 8);
    }

    // PV: o[t](16 x 16dh) accumulated f32; A = P[m=lane&15][k], B = VT
    const int nkc = (nkt * 16 + 31) >> 5;     // 32-wide k-chunks
    floatx4 o[4] = {zf, zf, zf, zf};
    const int vbase = 16 * wave + 32;         // VT col of k_rel = 0
    for (int c = 0; c < nkc; ++c) {
      const f16x8 pa = *(const f16x8*)(Pw + l16 * PS + c * 32 + quad * 8);
#pragma unroll
      for (int t = 0; t < 4; ++t) {
        const f16x8 vb = *(const f16x8*)(VT + (t * 16 + l16) * VTS + vbase + c * 32 + quad * 8);
        o[t] = __builtin_amdgcn_mfma_f32_16x16x32_f16(pa, vb, o[t], 0, 0, 0);
      }
    }

    // normalize + stage O into Pw ([m][dh], stride PS), then coalesced store
#pragma unroll
    for (int t = 0; t < 4; ++t) {
#pragma unroll
      for (int r = 0; r < 4; ++r)
        Pw[(quad * 4 + r) * PS + t * 16 + l16] = (_Float16)(o[t][r] / lsum[r]);
    }
    const int orow = lane >> 2, oseg = lane & 3;
#pragma unroll
    for (int hseg = 0; hseg < 2; ++hseg) {
      const f16x8 ov = *(const f16x8*)(Pw + orow * PS + oseg * 16 + hseg * 8);
      bf16 ob[8];
#pragma unroll
      for (int s = 0; s < 8; ++s) ob[s] = (bf16)(float)ov[s];
      *(uint4*)(attn_out + (xb + i0 + orow) * 1024 + h * 64 + oseg * 16 + hseg * 8) =
          *(const uint4*)ob;
    }
    return;
  }

  // ---- fallback: rarely taken; plain per-lane scalar loop (128 q/block) ----
  if (tid < 128) {
    const int i = Q0 + tid;
    float l = 0.f;
    float oacc[64];
#pragma unroll
    for (int u = 0; u < 64; ++u) oacc[u] = 0.f;
    float qv[64];
#pragma unroll
    for (int u = 0; u < 64; ++u) qv[u] = (float)Xh[(xb + i) * 3072 + qo + u];
    for (int tt = -kk; tt <= kk; ++tt) {
      const int j = i + (int)((long long)tt * dil);
      if (j < 0 || j >= 2048) continue;
      float s = 0.f;
      for (int u = 0; u < 64; ++u) s += qv[u] * (float)Xh[(xb + j) * 3072 + ko + u];
      const float pe = __expf(s * 0.125f);
      l += pe;
      for (int u = 0; u < 64; ++u) oacc[u] += pe * (float)Xh[(xb + j) * 3072 + vo + u];
    }
    for (int u = 0; u < 64; ++u)
      attn_out[(xb + i) * 1024 + h * 64 + u] = (bf16)(oacc[u] / l);
  }
}

// ---------------------------------------------------------------------------
extern "C" void kernel_launch(void* const* d_in, const int* in_sizes, int n_in,
                              void* d_out, int out_size, void* d_ws, size_t ws_size,
                              hipStream_t stream) {
  const float* x  = (const float*)d_in[0];
  const float* Wq = (const float*)d_in[1];
  const float* bq = (const float*)d_in[2];
  const float* Wk = (const float*)d_in[3];
  const float* bk = (const float*)d_in[4];
  const float* Wv = (const float*)d_in[5];
  const float* bv = (const float*)d_in[6];
  const float* Wo = (const float*)d_in[7];
  const float* bo = (const float*)d_in[8];
  const int* kp   = (const int*)d_in[9];
  const int* dp   = (const int*)d_in[10];
  float* out = (float*)d_out;

  bf16*   xbf   = (bf16*)d_ws;                   // 8388608  (B,N,D) bf16
  bf16*   WTqkv = xbf + 8388608;                 // 3072*1024 bf16
  bf16*   WoT   = WTqkv + 3072 * 1024;           // 1024*1024 bf16
  __half* qkv   = (__half*)(WoT + 1024 * 1024);  // 8192*3072 f16 row-major
  bf16*   attnO = xbf;                           // alias: (B,N,1024) bf16

  prep_kernel<<<dim3(3072), 256, 0, stream>>>(x, Wq, Wk, Wv, Wo, xbf, WTqkv, WoT);

  gemm_qkv_8ph<<<dim3(32, 16), 512, 0, stream>>>(xbf, WTqkv, bq, bk, bv, qkv);

  dilated_attn_mfma_kernel<<<dim3(1024), 512, 0, stream>>>(qkv, attnO, kp, dp);

  gemm_proj<<<dim3(64, 8), 256, 0, stream>>>(attnO, WoT, bo, out);
}

// Round 18
// 207.563 us; speedup vs baseline: 1.3003x; 1.0322x over previous
//
#include <hip/hip_runtime.h>
#include <hip/hip_bf16.h>
#include <hip/hip_fp16.h>
#include <stdint.h>

using bf16 = __hip_bfloat16;

typedef __bf16    bf16x8 __attribute__((ext_vector_type(8)));
typedef float     floatx4 __attribute__((ext_vector_type(4)));
typedef _Float16  f16x8 __attribute__((ext_vector_type(8)));

typedef __attribute__((address_space(3))) void as3_void;
typedef __attribute__((address_space(1))) void as1_void;

// async global->LDS, 16B/lane; LDS dest is wave-uniform base + lane*16.
#define GLD_LDS16(gp, lp) \
  __builtin_amdgcn_global_load_lds((as1_void*)(uintptr_t)(gp), (as3_void*)(uintptr_t)(lp), 16, 0, 0)

#define FENCE() asm volatile("" ::: "memory")
#define BAR()   do { FENCE(); __builtin_amdgcn_s_barrier(); FENCE(); } while (0)
// pin everything (MFMAs + their compiler-inserted lgkm waits) before the
// following barrier; no lgkmcnt(0) — compiler interleaves fine-grained waits.
#define PIN()   __builtin_amdgcn_sched_barrier(0)

// ---------------------------------------------------------------------------
// prep: blocks 0..1023 transpose W (fp32 [k][n] -> bf16 [n][k]); blocks
// 1024..3071 convert x fp32->bf16 (32 B stores/thread).
// ---------------------------------------------------------------------------
__global__ __launch_bounds__(256) void prep_kernel(
    const float* __restrict__ x,
    const float* __restrict__ Wq, const float* __restrict__ Wk,
    const float* __restrict__ Wv, const float* __restrict__ Wo,
    bf16* __restrict__ xbf, bf16* __restrict__ WTqkv, bf16* __restrict__ WoT) {
  __shared__ float tile[64 * 68];
  const int blk = blockIdx.x;
  const int tid = threadIdx.x;
  if (blk < 1024) {
    const int z = blk >> 8, t = blk & 255;
    const float* src = (z == 0) ? Wq : (z == 1) ? Wk : (z == 2) ? Wv : Wo;
    bf16* dst = (z < 3) ? (WTqkv + (size_t)z * 1024 * 1024) : WoT;
    const int nbase = (t & 15) * 64, kbase = (t >> 4) * 64;
    const int r1 = tid >> 4, c1 = tid & 15;
#pragma unroll
    for (int it = 0; it < 4; ++it) {
      const int row = r1 + it * 16;
      const float4 v = *(const float4*)(src + (size_t)(kbase + row) * 1024 + nbase + c1 * 4);
      *(float4*)(tile + row * 68 + c1 * 4) = v;
    }
    __syncthreads();
    const int c2 = tid & 7, n2 = tid >> 3;
#pragma unroll
    for (int it2 = 0; it2 < 2; ++it2) {
      const int n = n2 + it2 * 32;
      bf16 o[8];
#pragma unroll
      for (int s = 0; s < 8; ++s) o[s] = (bf16)tile[(8 * c2 + s) * 68 + n];
      *(uint4*)(dst + (size_t)(nbase + n) * 1024 + kbase + 8 * c2) = *(const uint4*)o;
    }
  } else {
    const size_t basei = ((size_t)(blk - 1024) * 256 + tid) * 16;
#pragma unroll
    for (int h = 0; h < 2; ++h) {
      const float4 a = *(const float4*)(x + basei + h * 8);
      const float4 b = *(const float4*)(x + basei + h * 8 + 4);
      bf16 o[8] = {(bf16)a.x, (bf16)a.y, (bf16)a.z, (bf16)a.w,
                   (bf16)b.x, (bf16)b.y, (bf16)b.z, (bf16)b.w};
      *(uint4*)(xbf + basei + h * 8) = *(const uint4*)o;
    }
  }
}

// ---------------------------------------------------------------------------
// QKV GEMM — R8 kernel verbatim (measured 53-55 us, ~950 TF, MfmaUtil 39%).
// ---------------------------------------------------------------------------
#define SAU(bufi, u, kt) \
  GLD_LDS16(A + abase + (uint64_t)(u) * 65536 + (uint64_t)(kt) * 64, \
            (char*)Asp[bufi] + (u) * 8192 + ldst)
#define SBU(bufi, u, kt) \
  GLD_LDS16(Bt + bbase + (uint64_t)(u) * 65536 + (uint64_t)(kt) * 64, \
            (char*)Bsp[bufi] + (u) * 8192 + ldst)

#define RDA2(bufi, mb) do { \
    const char* _p = (const char*)Asp[bufi] + (wm * 64 + (mb) * 16 + l16) * 128; \
    af[0][0] = *(const bf16x8*)(_p + pcb0); \
    af[0][1] = *(const bf16x8*)(_p + pcb1); \
    af[1][0] = *(const bf16x8*)(_p + 2048 + pcb0); \
    af[1][1] = *(const bf16x8*)(_p + 2048 + pcb1); \
  } while (0)

#define RDB6(bufi) do { \
    const char* _p = (const char*)Bsp[bufi] + (wn * 96 + l16) * 128; \
    _Pragma("unroll") for (int _j = 0; _j < 6; ++_j) { \
      bfr[_j][0] = *(const bf16x8*)(_p + _j * 2048 + pcb0); \
      bfr[_j][1] = *(const bf16x8*)(_p + _j * 2048 + pcb1); \
    } \
  } while (0)

#define MMQ24(mb) do { \
    _Pragma("unroll") for (int _i = 0; _i < 2; ++_i) \
      _Pragma("unroll") for (int _j = 0; _j < 6; ++_j) \
        _Pragma("unroll") for (int _k = 0; _k < 2; ++_k) \
          acc[(mb) + _i][_j] = __builtin_amdgcn_mfma_f32_16x16x32_bf16( \
              af[_i][_k], bfr[_j][_k], acc[(mb) + _i][_j], 0, 0, 0); \
  } while (0)

__global__ __launch_bounds__(512, 2) void gemm_qkv_8ph(
    const bf16* __restrict__ A, const bf16* __restrict__ Bt,
    const float* __restrict__ b0, const float* __restrict__ b1, const float* __restrict__ b2,
    __half* __restrict__ qkv) {
  const int t    = threadIdx.x;
  const int m0   = blockIdx.x * 256;
  const int n0   = blockIdx.y * 192;
  const int lane = t & 63;
  const int wave = t >> 6;      // 0..7
  const int wm   = wave >> 1;   // 0..3 -> 64-row strip
  const int wn   = wave & 1;    // 0..1 -> 96-col strip
  const int quad = lane >> 4;
  const int l16  = lane & 15;

  // A dbuf 2x32KB @0, B dbuf 2x24KB @65536; epilogue reuses all 112KB.
  __shared__ alignas(16) char smem[114688];
  bf16* const Asp[2] = {(bf16*)smem, (bf16*)(smem + 32768)};
  bf16* const Bsp[2] = {(bf16*)(smem + 65536), (bf16*)(smem + 90112)};

  const int srt = t >> 3;
  const int sct = ((t & 7) ^ (srt & 7)) << 3;
  const uint64_t abase = (uint64_t)(m0 + srt) * 1024 + sct;
  const uint64_t bbase = (uint64_t)(n0 + srt) * 1024 + sct;
  const int ldst = t * 16;

  const int pcb0 = ((quad) ^ (l16 & 7)) << 4;
  const int pcb1 = ((4 + quad) ^ (l16 & 7)) << 4;

  floatx4 acc[4][6];
#pragma unroll
  for (int i = 0; i < 4; ++i)
#pragma unroll
    for (int j = 0; j < 6; ++j) {
      floatx4 z = {0.f, 0.f, 0.f, 0.f};
      acc[i][j] = z;
    }
  bf16x8 af[2][2], bfr[6][2];

  // prologue: t0 full (7 units) -> buf0; t1.B (3 units) -> buf1.
  SBU(0, 0, 0); SBU(0, 1, 0); SBU(0, 2, 0);
  SAU(0, 0, 0); SAU(0, 1, 0); SAU(0, 2, 0); SAU(0, 3, 0);
  SBU(1, 0, 1); SBU(1, 1, 1); SBU(1, 2, 1);
  asm volatile("s_waitcnt vmcnt(3)" ::: "memory");  // t0's 7 arrived
  BAR();

  for (int i = 0; i < 8; ++i) {
    const int kt1 = 2 * i + 1;
    const int kt2 = 2 * i + 2;
    const int kt3 = 2 * i + 3;
    const bool pf = (i < 7);

    // A1: read buf0 A[mb0-1]+B(all); stage buf1.A0-3
    RDA2(0, 0); RDB6(0);
    SAU(1, 0, kt1); SAU(1, 1, kt1); SAU(1, 2, kt1); SAU(1, 3, kt1);
    __builtin_amdgcn_s_setprio(1); MMQ24(0); __builtin_amdgcn_s_setprio(0);
    PIN();
    BAR();

    // A2: read buf0 A[mb2-3]; stage buf0.B0-2; drain t1
    RDA2(0, 2);
    if (pf) { SBU(0, 0, kt2); SBU(0, 1, kt2); SBU(0, 2, kt2); }
    __builtin_amdgcn_s_setprio(1); MMQ24(2); __builtin_amdgcn_s_setprio(0);
    PIN();
    if (pf) { asm volatile("s_waitcnt vmcnt(3)" ::: "memory"); }
    else    { asm volatile("s_waitcnt vmcnt(0)" ::: "memory"); }
    BAR();

    // B1: read buf1 A[mb0-1]+B(all); stage buf0.A0-3
    RDA2(1, 0); RDB6(1);
    if (pf) { SAU(0, 0, kt2); SAU(0, 1, kt2); SAU(0, 2, kt2); SAU(0, 3, kt2); }
    __builtin_amdgcn_s_setprio(1); MMQ24(0); __builtin_amdgcn_s_setprio(0);
    PIN();
    BAR();

    // B2: read buf1 A[mb2-3]; stage buf1.B0-2; drain t2
    RDA2(1, 2);
    if (pf) { SBU(1, 0, kt3); SBU(1, 1, kt3); SBU(1, 2, kt3); }
    __builtin_amdgcn_s_setprio(1); MMQ24(2); __builtin_amdgcn_s_setprio(0);
    PIN();
    if (pf) { asm volatile("s_waitcnt vmcnt(3)" ::: "memory"); }
    BAR();
  }

  // epilogue: bias + f16; single LDS restage, one barrier, 12 f16x8 stores.
  float bvs[6];
#pragma unroll
  for (int nj = 0; nj < 6; ++nj) {
    const int n = n0 + wn * 96 + nj * 16 + l16;
    const int which = n >> 10;
    const int c = n & 1023;
    bvs[nj] = ((which == 0) ? b0 : (which == 1) ? b1 : b2)[c];
  }
  _Float16* stg = (_Float16*)smem;
#pragma unroll
  for (int mb = 0; mb < 4; ++mb)
#pragma unroll
    for (int nj = 0; nj < 6; ++nj)
#pragma unroll
      for (int r = 0; r < 4; ++r)
        stg[(wm * 64 + mb * 16 + quad * 4 + r) * 200 + wn * 96 + nj * 16 + l16] =
            (_Float16)(acc[mb][nj][r] + bvs[nj]);
  BAR();
#pragma unroll
  for (int rep = 0; rep < 12; ++rep) {
    const int cc = t + rep * 512;     // 0..6143 = 256 rows x 24 chunks
    const int rl = cc / 24;
    const int ch = cc - rl * 24;
    const f16x8 v = *(const f16x8*)(stg + rl * 200 + ch * 8);
    *(f16x8*)((_Float16*)qkv + (size_t)(m0 + rl) * 3072 + n0 + ch * 8) = v;
  }
}

// ---------------------------------------------------------------------------
// Projection GEMM — R13: R8 schedule ported. BM=256 x BN=128, BK=64,
// grid 32x8 = 256 blocks = EXACTLY 1 round. 8 waves (4M x 2N), per-wave
// 64x64 = acc[4][4]. LDS: A dbuf 2x32KB + B dbuf 2x16KB = 96KB.
// Stage slots: A1 t1.A x4 | A2 t2.B x2 | B1 t2.A x4 | B2 t3.B x2;
// vmcnt(2) at A2/B2 end (8 outstanding - 6 oldest = prev tile complete).
// Out fp32 + bias, direct stores (16-lane 64B segments).
// ---------------------------------------------------------------------------
#define PSAU(bufi, u, kt) \
  GLD_LDS16(A + pab + (uint64_t)(u) * 65536 + (uint64_t)(kt) * 64, \
            (char*)PAs[bufi] + (u) * 8192 + ldst)
#define PSBU(bufi, u, kt) \
  GLD_LDS16(Bt + pbb + (uint64_t)(u) * 65536 + (uint64_t)(kt) * 64, \
            (char*)PBs[bufi] + (u) * 8192 + ldst)

#define PRDA(bufi, mb) do { \
    const char* _p = (const char*)PAs[bufi] + (wm * 64 + (mb) * 16 + l16) * 128; \
    af[0][0] = *(const bf16x8*)(_p + pcb0); \
    af[0][1] = *(const bf16x8*)(_p + pcb1); \
    af[1][0] = *(const bf16x8*)(_p + 2048 + pcb0); \
    af[1][1] = *(const bf16x8*)(_p + 2048 + pcb1); \
  } while (0)

#define PRDB(bufi) do { \
    const char* _p = (const char*)PBs[bufi] + (wn * 64 + l16) * 128; \
    _Pragma("unroll") for (int _j = 0; _j < 4; ++_j) { \
      bfr[_j][0] = *(const bf16x8*)(_p + _j * 2048 + pcb0); \
      bfr[_j][1] = *(const bf16x8*)(_p + _j * 2048 + pcb1); \
    } \
  } while (0)

#define PMM16(mb) do { \
    _Pragma("unroll") for (int _i = 0; _i < 2; ++_i) \
      _Pragma("unroll") for (int _j = 0; _j < 4; ++_j) \
        _Pragma("unroll") for (int _k = 0; _k < 2; ++_k) \
          acc[(mb) + _i][_j] = __builtin_amdgcn_mfma_f32_16x16x32_bf16( \
              af[_i][_k], bfr[_j][_k], acc[(mb) + _i][_j], 0, 0, 0); \
  } while (0)

__global__ __launch_bounds__(512, 2) void gemm_proj(
    const bf16* __restrict__ A, const bf16* __restrict__ Bt,
    const float* __restrict__ bias, float* __restrict__ fout) {
  const int t    = threadIdx.x;
  const int m0   = blockIdx.x * 256;
  const int n0   = blockIdx.y * 128;
  const int lane = t & 63;
  const int wave = t >> 6;      // 0..7
  const int wm   = wave >> 1;   // 0..3 -> 64-row strip
  const int wn   = wave & 1;    // 0..1 -> 64-col strip
  const int quad = lane >> 4;
  const int l16  = lane & 15;

  __shared__ alignas(16) char smem[98304];  // A 2x32KB @0, B 2x16KB @65536
  bf16* const PAs[2] = {(bf16*)smem, (bf16*)(smem + 32768)};
  bf16* const PBs[2] = {(bf16*)(smem + 65536), (bf16*)(smem + 81920)};

  const int srt = t >> 3;
  const int sct = ((t & 7) ^ (srt & 7)) << 3;
  const uint64_t pab = (uint64_t)(m0 + srt) * 1024 + sct;
  const uint64_t pbb = (uint64_t)(n0 + srt) * 1024 + sct;
  const int ldst = t * 16;

  const int pcb0 = ((quad) ^ (l16 & 7)) << 4;
  const int pcb1 = ((4 + quad) ^ (l16 & 7)) << 4;

  floatx4 acc[4][4];
#pragma unroll
  for (int i = 0; i < 4; ++i)
#pragma unroll
    for (int j = 0; j < 4; ++j) {
      floatx4 z = {0.f, 0.f, 0.f, 0.f};
      acc[i][j] = z;
    }
  bf16x8 af[2][2], bfr[4][2];

  // prologue: t0 full (B0,B1,A0-3 = 6) -> buf0; t1.B (2) -> buf1.
  PSBU(0, 0, 0); PSBU(0, 1, 0);
  PSAU(0, 0, 0); PSAU(0, 1, 0); PSAU(0, 2, 0); PSAU(0, 3, 0);
  PSBU(1, 0, 1); PSBU(1, 1, 1);
  asm volatile("s_waitcnt vmcnt(2)" ::: "memory");  // t0's 6 arrived
  BAR();

  for (int i = 0; i < 8; ++i) {
    const int kt1 = 2 * i + 1;
    const int kt2 = 2 * i + 2;
    const int kt3 = 2 * i + 3;
    const bool pf = (i < 7);

    // A1: read buf0 A[mb0-1]+B(all); stage buf1.A0-3
    PRDA(0, 0); PRDB(0);
    PSAU(1, 0, kt1); PSAU(1, 1, kt1); PSAU(1, 2, kt1); PSAU(1, 3, kt1);
    __builtin_amdgcn_s_setprio(1); PMM16(0); __builtin_amdgcn_s_setprio(0);
    PIN();
    BAR();

    // A2: read buf0 A[mb2-3]; stage buf0.B0-1; drain t1
    PRDA(0, 2);
    if (pf) { PSBU(0, 0, kt2); PSBU(0, 1, kt2); }
    __builtin_amdgcn_s_setprio(1); PMM16(2); __builtin_amdgcn_s_setprio(0);
    PIN();
    if (pf) { asm volatile("s_waitcnt vmcnt(2)" ::: "memory"); }
    else    { asm volatile("s_waitcnt vmcnt(0)" ::: "memory"); }
    BAR();

    // B1: read buf1 A[mb0-1]+B(all); stage buf0.A0-3
    PRDA(1, 0); PRDB(1);
    if (pf) { PSAU(0, 0, kt2); PSAU(0, 1, kt2); PSAU(0, 2, kt2); PSAU(0, 3, kt2); }
    __builtin_amdgcn_s_setprio(1); PMM16(0); __builtin_amdgcn_s_setprio(0);
    PIN();
    BAR();

    // B2: read buf1 A[mb2-3]; stage buf1.B0-1; drain t2
    PRDA(1, 2);
    if (pf) { PSBU(1, 0, kt3); PSBU(1, 1, kt3); }
    __builtin_amdgcn_s_setprio(1); PMM16(2); __builtin_amdgcn_s_setprio(0);
    PIN();
    if (pf) { asm volatile("s_waitcnt vmcnt(2)" ::: "memory"); }
    BAR();
  }

  // epilogue: bias + fp32 direct stores (16-lane 64B segments per instr).
  float bvs[4];
#pragma unroll
  for (int nj = 0; nj < 4; ++nj)
    bvs[nj] = bias[n0 + wn * 64 + nj * 16 + l16];
#pragma unroll
  for (int mb = 0; mb < 4; ++mb)
#pragma unroll
    for (int nj = 0; nj < 4; ++nj)
#pragma unroll
      for (int r = 0; r < 4; ++r) {
        const int m = m0 + wm * 64 + mb * 16 + quad * 4 + r;
        const int n = n0 + wn * 64 + nj * 16 + l16;
        fout[(uint64_t)m * 1024 + n] = acc[mb][nj][r] + bvs[nj];
      }
}

// ---------------------------------------------------------------------------
// Dilated attention — R8 version verbatim (64 q/block, 256 thr, 2048 blocks;
// R12's 128q/512thr variant REVERTED: it cost +13 us non-QKV).
// Reads Q/K/V from row-major qkv (B,N,3072) f16; writes (B,N,1024) bf16.
// ---------------------------------------------------------------------------
#define RMAXA 32
#define VTS 176       // VT col stride (halves)
#define PS  104       // P row stride (halves)

__global__ __launch_bounds__(256) void dilated_attn_mfma_kernel(
    const __half* __restrict__ qkv, bf16* __restrict__ attn_out,
    const int* __restrict__ kptr, const int* __restrict__ dptr) {
  const int tid  = threadIdx.x;
  const int wave = tid >> 6, lane = tid & 63;
  const int quad = lane >> 4, l16 = lane & 15;
  const int bh = blockIdx.x >> 5;       // 32 query-blocks of 64 per (b,h)
  const int Q0 = (blockIdx.x & 31) * 64;
  const int b  = bh >> 4, h = bh & 15;
  const int kk  = kptr[0];
  const int dil = dptr[0];
  const int R   = kk * dil;
  const size_t xb = (size_t)b * 2048;
  const int qo = h * 64, ko = 1024 + h * 64, vo = 2048 + h * 64;
  const _Float16* Xh = (const _Float16*)qkv;

  __shared__ alignas(16) _Float16 smem[64 * VTS + 4 * 16 * PS];  // 35840 B
  _Float16* VT = smem;
  _Float16* Pw = smem + 64 * VTS + wave * 16 * PS;

  const bool fast = (R <= RMAXA) && (dil >= 1);

  if (fast) {
    // zero-fill VT + P (guards / pad cols must be 0, not stale/NaN bits)
    {
      const int nch = (64 * VTS + 4 * 16 * PS) / 8;
      const f16x8 z = {0, 0, 0, 0, 0, 0, 0, 0};
      for (int c = tid; c < nch; c += 256) ((f16x8*)smem)[c] = z;
    }
    __syncthreads();

    // stage V transposed: VT[dh][col], col = j - (Q0-R) + 32
    const int jlo = Q0 - R;  // unclamped
    const int lo = (jlo > 0) ? jlo : 0;
    const int hi = (Q0 + 63 + R < 2047) ? Q0 + 63 + R : 2047;
    const int nrows = hi - lo + 1;
    for (int idx = tid; idx < nrows * 8; idx += 256) {
      const int r = idx >> 3, c = idx & 7;
      const int j = lo + r;
      const f16x8 v = *(const f16x8*)(Xh + (xb + j) * 3072 + vo + c * 8);
      const int col = j - jlo + 32;
#pragma unroll
      for (int s = 0; s < 8; ++s) VT[(c * 8 + s) * VTS + col] = v[s];
    }
    __syncthreads();

    const int i0 = Q0 + wave * 16;
    // Q A-frags (2 k-chunks of 32 over DH=64)
    const f16x8 a0 = *(const f16x8*)(Xh + (xb + i0 + l16) * 3072 + qo + quad * 8);
    const f16x8 a1 = *(const f16x8*)(Xh + (xb + i0 + l16) * 3072 + qo + 32 + quad * 8);

    const int nkt = (16 + 2 * R + 15) >> 4;   // key tiles of 16
    const int jw0 = i0 - R;                   // wave key-window start
    float lsum[4] = {0.f, 0.f, 0.f, 0.f};
    const floatx4 zf = {0.f, 0.f, 0.f, 0.f};

    for (int kt = 0; kt < nkt; ++kt) {
      const int j0 = jw0 + 16 * kt;
      const int jn = j0 + l16;                        // this lane's key
      const int jc = (jn < 0) ? 0 : (jn > 2047 ? 2047 : jn);
      const f16x8 k0v = *(const f16x8*)(Xh + (xb + jc) * 3072 + ko + quad * 8);
      const f16x8 k1v = *(const f16x8*)(Xh + (xb + jc) * 3072 + ko + 32 + quad * 8);
      floatx4 s4 = __builtin_amdgcn_mfma_f32_16x16x32_f16(a0, k0v, zf, 0, 0, 0);
      s4 = __builtin_amdgcn_mfma_f32_16x16x32_f16(a1, k1v, s4, 0, 0, 0);
#pragma unroll
      for (int r = 0; r < 4; ++r) {
        const int m = quad * 4 + r;
        const int d = jn - (i0 + m);
        const bool valid = ((unsigned)jn < 2048u) && (d >= -R) && (d <= R) && (d % dil == 0);
        const float pe = valid ? __expf(s4[r] * 0.125f) : 0.f;
        lsum[r] += pe;
        Pw[m * PS + kt * 16 + l16] = (_Float16)pe;
      }
    }
    // row sums: reduce across the 16 lanes of each quad
#pragma unroll
    for (int r = 0; r < 4; ++r) {
      lsum[r] += __shfl_xor(lsum[r], 1);
      lsum[r] += __shfl_xor(lsum[r], 2);
      lsum[r] += __shfl_xor(lsum[r], 4);
      lsum[r] += __shfl_xor(lsum[r], 8);
    }

    // PV: o[t](16 x 16dh) accumulated f32; A = P[m=lane&15][k], B = VT
    const int nkc = (nkt * 16 + 31) >> 5;     // 32-wide k-chunks
    floatx4 o[4] = {zf, zf, zf, zf};
    const int vbase = 16 * wave + 32;         // VT col of k_rel = 0
    for (int c = 0; c < nkc; ++c) {
      const f16x8 pa = *(const f16x8*)(Pw + l16 * PS + c * 32 + quad * 8);
#pragma unroll
      for (int t = 0; t < 4; ++t) {
        const f16x8 vb = *(const f16x8*)(VT + (t * 16 + l16) * VTS + vbase + c * 32 + quad * 8);
        o[t] = __builtin_amdgcn_mfma_f32_16x16x32_f16(pa, vb, o[t], 0, 0, 0);
      }
    }

    // normalize + stage O into Pw ([m][dh], stride PS), then coalesced store
#pragma unroll
    for (int t = 0; t < 4; ++t) {
#pragma unroll
      for (int r = 0; r < 4; ++r)
        Pw[(quad * 4 + r) * PS + t * 16 + l16] = (_Float16)(o[t][r] / lsum[r]);
    }
    const int orow = lane >> 2, oseg = lane & 3;
#pragma unroll
    for (int hseg = 0; hseg < 2; ++hseg) {
      const f16x8 ov = *(const f16x8*)(Pw + orow * PS + oseg * 16 + hseg * 8);
      bf16 ob[8];
#pragma unroll
      for (int s = 0; s < 8; ++s) ob[s] = (bf16)(float)ov[s];
      *(uint4*)(attn_out + (xb + i0 + orow) * 1024 + h * 64 + oseg * 16 + hseg * 8) =
          *(const uint4*)ob;
    }
    return;
  }

  // ---- fallback: rarely taken; plain per-lane scalar loop ----
  if (tid < 64) {
    const int i = Q0 + tid;
    float l = 0.f;
    float oacc[64];
#pragma unroll
    for (int u = 0; u < 64; ++u) oacc[u] = 0.f;
    float qv[64];
#pragma unroll
    for (int u = 0; u < 64; ++u) qv[u] = (float)Xh[(xb + i) * 3072 + qo + u];
    for (int tt = -kk; tt <= kk; ++tt) {
      const int j = i + (int)((long long)tt * dil);
      if (j < 0 || j >= 2048) continue;
      float s = 0.f;
      for (int u = 0; u < 64; ++u) s += qv[u] * (float)Xh[(xb + j) * 3072 + ko + u];
      const float pe = __expf(s * 0.125f);
      l += pe;
      for (int u = 0; u < 64; ++u) oacc[u] += pe * (float)Xh[(xb + j) * 3072 + vo + u];
    }
    for (int u = 0; u < 64; ++u)
      attn_out[(xb + i) * 1024 + h * 64 + u] = (bf16)(oacc[u] / l);
  }
}

// ---------------------------------------------------------------------------
extern "C" void kernel_launch(void* const* d_in, const int* in_sizes, int n_in,
                              void* d_out, int out_size, void* d_ws, size_t ws_size,
                              hipStream_t stream) {
  const float* x  = (const float*)d_in[0];
  const float* Wq = (const float*)d_in[1];
  const float* bq = (const float*)d_in[2];
  const float* Wk = (const float*)d_in[3];
  const float* bk = (const float*)d_in[4];
  const float* Wv = (const float*)d_in[5];
  const float* bv = (const float*)d_in[6];
  const float* Wo = (const float*)d_in[7];
  const float* bo = (const float*)d_in[8];
  const int* kp   = (const int*)d_in[9];
  const int* dp   = (const int*)d_in[10];
  float* out = (float*)d_out;

  bf16*   xbf   = (bf16*)d_ws;                   // 8388608  (B,N,D) bf16
  bf16*   WTqkv = xbf + 8388608;                 // 3072*1024 bf16
  bf16*   WoT   = WTqkv + 3072 * 1024;           // 1024*1024 bf16
  __half* qkv   = (__half*)(WoT + 1024 * 1024);  // 8192*3072 f16 row-major
  bf16*   attnO = xbf;                           // alias: (B,N,1024) bf16

  prep_kernel<<<dim3(3072), 256, 0, stream>>>(x, Wq, Wk, Wv, Wo, xbf, WTqkv, WoT);

  gemm_qkv_8ph<<<dim3(32, 16), 512, 0, stream>>>(xbf, WTqkv, bq, bk, bv, qkv);

  dilated_attn_mfma_kernel<<<dim3(2048), 256, 0, stream>>>(qkv, attnO, kp, dp);

  gemm_proj<<<dim3(32, 8), 512, 0, stream>>>(attnO, WoT, bo, out);
}